// Round 12
// baseline (63.674 us; speedup 1.0000x reference)
//
#include <hip/hip_runtime.h>

#define CLC_NATOMS 8192
#define CLC_NSHIFT 14
#define CLC_NROWS (CLC_NSHIFT * CLC_NATOMS)  // 114688 rows = (k, i)
#define CLC_NTILE 112                        // scan tiles of 1024 rows
#define CLC_NCELL 512                        // 8x8x8 spatial bins
#define CLC_CAP 128                          // max hits per row (k=0 max ~90)
#define CLC_C2 ((float)(5.2 * 5.2))          // f32 compare (JAX weak promotion)
#define CLC_R 5.35f                          // candidate interval half-width

__device__ const int clc_shifts[CLC_NSHIFT][3] = {
    {0, 0, 0},
    {-1, 0, 0}, {-1, -1, 0}, {0, -1, 0}, {1, -1, 0},
    {-1, 1, -1}, {0, 1, -1}, {1, 1, -1}, {-1, 0, -1},
    {0, 0, -1}, {1, 0, -1}, {-1, -1, -1}, {0, -1, -1}, {1, -1, -1}};

// Module-owned scratch (d_ws unused). Everything read is rewritten each call.
__device__ float4 clc_pp[CLC_NATOMS];      // wrapped coords
__device__ float4 clc_sorted[CLC_NATOMS];  // bin-sorted coords, .w = original i
__device__ unsigned clc_cstart[CLC_NCELL + 1];
__device__ int clc_jbuf[(size_t)CLC_NROWS * CLC_CAP];  // per-row sorted hit j's
__device__ unsigned clc_cnt[CLC_NROWS];
__device__ unsigned clc_off[CLC_NROWS];    // exclusive offset WITHIN tile
__device__ unsigned clc_tot[CLC_NTILE];    // per-tile totals
__device__ float4 clc_dg;                  // cell diagonal
__device__ float4 clc_cinv;                // 8/diag per axis
__device__ float4 clc_sf[CLC_NSHIFT];      // s * diag (f32, __fmul_rn)

__device__ __forceinline__ int clc_cellof(const float4& p, const float4& cinv) {
  int cx = min(7, (int)(p.x * cinv.x));
  int cy = min(7, (int)(p.y * cinv.y));
  int cz = min(7, (int)(p.z * cinv.z));
  return (cz * 8 + cy) * 8 + cx;  // x fastest -> contiguous x-runs
}

// --- K1: wrap (+ thread-0 writes the f64-derived constants) -----------------
// frac = x @ inv(cell); frac -= floor(frac); w = frac @ cell   (f32 per-op RN)
__global__ __launch_bounds__(256) void clc_wrap(const float* __restrict__ coords,
                                                const float* __restrict__ cell) {
  int i = blockIdx.x * blockDim.x + threadIdx.x;
  if (i >= CLC_NATOMS) return;
  if (i == 0) {
    float dgx = (float)sqrt((double)cell[0] * cell[0] + (double)cell[3] * cell[3] +
                            (double)cell[6] * cell[6]);
    float dgy = (float)sqrt((double)cell[1] * cell[1] + (double)cell[4] * cell[4] +
                            (double)cell[7] * cell[7]);
    float dgz = (float)sqrt((double)cell[2] * cell[2] + (double)cell[5] * cell[5] +
                            (double)cell[8] * cell[8]);
    clc_dg = make_float4(dgx, dgy, dgz, 0.f);
    clc_cinv = make_float4(8.0f / dgx, 8.0f / dgy, 8.0f / dgz, 0.f);
    for (int k = 0; k < CLC_NSHIFT; ++k)
      clc_sf[k] = make_float4(__fmul_rn((float)clc_shifts[k][0], dgx),
                              __fmul_rn((float)clc_shifts[k][1], dgy),
                              __fmul_rn((float)clc_shifts[k][2], dgz), 0.f);
  }
  double a00 = cell[0], a01 = cell[1], a02 = cell[2];
  double a10 = cell[3], a11 = cell[4], a12 = cell[5];
  double a20 = cell[6], a21 = cell[7], a22 = cell[8];
  double det = a00 * (a11 * a22 - a12 * a21) - a01 * (a10 * a22 - a12 * a20) +
               a02 * (a10 * a21 - a11 * a20);
  double id = 1.0 / det;
  float inv[3][3];
  inv[0][0] = (float)((a11 * a22 - a12 * a21) * id);
  inv[0][1] = (float)(-(a01 * a22 - a02 * a21) * id);
  inv[0][2] = (float)((a01 * a12 - a02 * a11) * id);
  inv[1][0] = (float)(-(a10 * a22 - a12 * a20) * id);
  inv[1][1] = (float)((a00 * a22 - a02 * a20) * id);
  inv[1][2] = (float)(-(a00 * a12 - a02 * a10) * id);
  inv[2][0] = (float)((a10 * a21 - a11 * a20) * id);
  inv[2][1] = (float)(-(a00 * a21 - a01 * a20) * id);
  inv[2][2] = (float)((a00 * a11 - a01 * a10) * id);

  float x = coords[3 * i], y = coords[3 * i + 1], z = coords[3 * i + 2];
  float fr[3], w[3];
#pragma unroll
  for (int c = 0; c < 3; ++c) {
    float f = __fadd_rn(__fadd_rn(__fmul_rn(x, inv[0][c]), __fmul_rn(y, inv[1][c])),
                        __fmul_rn(z, inv[2][c]));
    fr[c] = __fsub_rn(f, floorf(f));
  }
#pragma unroll
  for (int c = 0; c < 3; ++c) {
    w[c] = __fadd_rn(
        __fadd_rn(__fmul_rn(fr[0], cell[0 * 3 + c]), __fmul_rn(fr[1], cell[1 * 3 + c])),
        __fmul_rn(fr[2], cell[2 * 3 + c]));
  }
  clc_pp[i] = make_float4(w[0], w[1], w[2], 0.0f);
}

// --- K2: single-block binsort: LDS hist -> LDS scan -> scatter --------------
// (block-local ordering only; intra-cell order nondeterministic but output-
//  invariant since hits become bits keyed by original index)
__global__ __launch_bounds__(1024) void clc_binsort() {
  __shared__ unsigned h[CLC_NCELL];
  __shared__ unsigned cfill[CLC_NCELL];
  int t = threadIdx.x;
  if (t < CLC_NCELL) h[t] = 0u;
  __syncthreads();
  float4 cinv = clc_cinv;
  int cid[8];
#pragma unroll
  for (int r = 0; r < 8; ++r) {
    int i = t + r * 1024;
    cid[r] = clc_cellof(clc_pp[i], cinv);
    atomicAdd(&h[cid[r]], 1u);
  }
  __syncthreads();
  unsigned v = (t < CLC_NCELL) ? h[t] : 0u;
  unsigned acc = v;
  for (int off = 1; off < CLC_NCELL; off <<= 1) {
    unsigned a = (t >= off && t < CLC_NCELL) ? h[t - off] : 0u;
    __syncthreads();
    if (t < CLC_NCELL) {
      acc += a;
      h[t] = acc;
    }
    __syncthreads();
  }
  if (t < CLC_NCELL) {
    clc_cstart[t] = acc - v;
    cfill[t] = acc - v;
  }
  if (t == CLC_NCELL - 1) clc_cstart[CLC_NCELL] = acc;
  __syncthreads();
#pragma unroll
  for (int r = 0; r < 8; ++r) {
    int i = t + r * 1024;
    unsigned pos = atomicAdd(&cfill[cid[r]], 1u);
    float4 p = clc_pp[i];
    p.w = __int_as_float(i);
    clc_sorted[pos] = p;
  }
}

// Slab prune: d2<=c2 forces shifted atom i into a cutoff-wide boundary slab.
__device__ __forceinline__ bool clc_alive(float xi, float yi, float zi, int sx, int sy,
                                          int sz, float dgx, float dgy, float dgz) {
  bool a = true;
  if (sx < 0) a = a && (xi >= dgx - 5.3f); else if (sx > 0) a = a && (xi <= 5.3f);
  if (sy < 0) a = a && (yi >= dgy - 5.3f); else if (sy > 0) a = a && (yi <= 5.3f);
  if (sz < 0) a = a && (zi >= dgz - 5.3f); else if (sz > 0) a = a && (zi <= 5.3f);
  return a;
}

// Candidate cell range on one axis (monotone-rounding safe, 0.14 slack).
__device__ __forceinline__ void clc_crange(float t, float ci, int& lo, int& hi) {
  lo = max(0, (int)(fmaxf(t - CLC_R, 0.f) * ci));
  hi = min(7, (int)(fmaxf(t + CLC_R, 0.f) * ci));
}

__device__ __forceinline__ unsigned clc_iscan(unsigned v, int lane) {
  for (int off = 1; off < 64; off <<= 1) {
    unsigned t = __shfl_up(v, off);
    if (lane >= off) v += t;
  }
  return v;
}

// --- K3: count: one wave per (k,i) row; cell-list candidates -> LDS bitmask
// -> in-wave expansion to a SORTED compact j-list + row count ----------------
__global__ __launch_bounds__(512) void clc_count() {
  __shared__ uint4 smask[8][64];  // 1KB mask per wave
  int wslot = threadIdx.x >> 6;
  int wv = blockIdx.x * 8 + wslot;
  int lane = threadIdx.x & 63;
  unsigned* lm = (unsigned*)smask[wslot];
  int k = wv >> 13, i = wv & (CLC_NATOMS - 1);

  float4 dg = clc_dg;
  float4 sc = clc_sf[k];
  int sx = clc_shifts[k][0], sy = clc_shifts[k][1], sz = clc_shifts[k][2];
  float4 pi = clc_pp[i];
  if (k != 0 && !clc_alive(pi.x, pi.y, pi.z, sx, sy, sz, dg.x, dg.y, dg.z)) {
    if (lane == 0) clc_cnt[wv] = 0u;
    return;
  }
  smask[wslot][lane] = make_uint4(0u, 0u, 0u, 0u);

  float4 cinv = clc_cinv;
  int xlo, xhi, ylo, yhi, zlo, zhi;
  clc_crange(__fadd_rn(pi.x, sc.x), cinv.x, xlo, xhi);
  clc_crange(__fadd_rn(pi.y, sc.y), cinv.y, ylo, yhi);
  clc_crange(__fadd_rn(pi.z, sc.z), cinv.z, zlo, zhi);

  for (int cz = zlo; cz <= zhi; ++cz) {
    for (int cy = ylo; cy <= yhi; ++cy) {
      int idb = (cz * 8 + cy) * 8;
      unsigned b = clc_cstart[idb + xlo], e = clc_cstart[idb + xhi + 1];
      for (unsigned t = b + lane; t < e; t += 64) {
        float4 pj = clc_sorted[t];
        int j = __float_as_int(pj.w);
        float dx = __fadd_rn(__fsub_rn(pi.x, pj.x), sc.x);
        float dy = __fadd_rn(__fsub_rn(pi.y, pj.y), sc.y);
        float dz = __fadd_rn(__fsub_rn(pi.z, pj.z), sc.z);
        float d2 = __fadd_rn(__fadd_rn(__fmul_rn(dx, dx), __fmul_rn(dy, dy)),
                             __fmul_rn(dz, dz));
        bool ok = (d2 <= CLC_C2) && (k != 0 || i < j);
        if (ok) atomicOr(&lm[(unsigned)j >> 5], 1u << (j & 31));
      }
    }
  }
  __threadfence_block();  // drain LDS atomics before cross-lane mask read

  const unsigned long long* mrow = (const unsigned long long*)lm;
  unsigned long long m0 = mrow[lane];       // j in [64*lane, 64*lane+64)
  unsigned long long m1 = mrow[64 + lane];  // j in [4096+64*lane, ...)
  unsigned c0 = (unsigned)__popcll(m0), c1 = (unsigned)__popcll(m1);
  unsigned s0 = clc_iscan(c0, lane);
  unsigned T0 = __shfl(s0, 63);
  unsigned e0 = s0 - c0;
  unsigned s1 = clc_iscan(c1, lane);
  unsigned T1 = __shfl(s1, 63);
  unsigned e1 = T0 + s1 - c1;

  size_t jb = (size_t)wv * CLC_CAP;
  unsigned p = e0;
  unsigned long long m = m0;
  while (m) {
    int b = __ffsll((long long)m) - 1;
    m &= m - 1;
    if (p < CLC_CAP) clc_jbuf[jb + p] = (lane << 6) + b;
    ++p;
  }
  p = e1;
  m = m1;
  while (m) {
    int b = __ffsll((long long)m) - 1;
    m &= m - 1;
    if (p < CLC_CAP) clc_jbuf[jb + p] = ((64 + lane) << 6) + b;
    ++p;
  }
  if (lane == 0) clc_cnt[wv] = min(T0 + T1, (unsigned)CLC_CAP);
}

// --- K4: per-1024-row tile exclusive scan + tile total ----------------------
__global__ __launch_bounds__(1024) void clc_s1() {
  __shared__ unsigned sd[1024];
  int t = threadIdx.x;
  int gid = blockIdx.x * 1024 + t;
  unsigned v = clc_cnt[gid];
  sd[t] = v;
  __syncthreads();
  unsigned acc = v;
  for (int off = 1; off < 1024; off <<= 1) {
    unsigned a = (t >= off) ? sd[t - off] : 0u;
    __syncthreads();
    acc += a;
    sd[t] = acc;
    __syncthreads();
  }
  clc_off[gid] = acc - v;
  if (t == 1023) clc_tot[blockIdx.x] = acc;
}

// --- K5: emit: one wave per row; wave computes its tile base by reducing the
// preceding tile totals (<=112, L2-hot), then lanes copy the compact j-list
// into the int32 stream [ i xP | j xP | (sx,sy,sz) xP ] coalesced ------------
__global__ __launch_bounds__(512) void clc_emit(int* __restrict__ out, int P) {
  int wv = blockIdx.x * 8 + (threadIdx.x >> 6);
  int lane = threadIdx.x & 63;
  unsigned c = clc_cnt[wv];   // wave-uniform
  if (c == 0) return;
  int tile = wv >> 10;        // 1024 rows per tile
  unsigned v = 0;
  if (lane < tile) v = clc_tot[lane];
  if (64 + lane < tile) v += clc_tot[64 + lane];
#pragma unroll
  for (int off = 32; off; off >>= 1) v += __shfl_down(v, off);
  unsigned tbase = __shfl(v, 0);

  unsigned off0 = clc_off[wv] + tbase;
  int k = wv >> 13, i = wv & (CLC_NATOMS - 1);
  int sx = clc_shifts[k][0], sy = clc_shifts[k][1], sz = clc_shifts[k][2];
  size_t jb = (size_t)wv * CLC_CAP;
  for (unsigned q = lane; q < c; q += 64) {
    unsigned p = off0 + q;
    if (p < (unsigned)P) {
      out[p] = i;
      out[P + p] = clc_jbuf[jb + q];
      unsigned sp = 2u * (unsigned)P + 3u * p;
      out[sp] = sx;
      out[sp + 1] = sy;
      out[sp + 2] = sz;
    }
  }
}

extern "C" void kernel_launch(void* const* d_in, const int* in_sizes, int n_in,
                              void* d_out, int out_size, void* d_ws, size_t ws_size,
                              hipStream_t stream) {
  const float* coords = (const float*)d_in[1];  // (1, N, 3) f32
  const float* cell = (const float*)d_in[2];    // (3, 3) f32
  int P = out_size / 5;

  clc_wrap<<<CLC_NATOMS / 256, 256, 0, stream>>>(coords, cell);
  clc_binsort<<<1, 1024, 0, stream>>>();
  clc_count<<<CLC_NROWS / 8, 512, 0, stream>>>();
  clc_s1<<<CLC_NTILE, 1024, 0, stream>>>();
  clc_emit<<<CLC_NROWS / 8, 512, 0, stream>>>((int*)d_out, P);
}

// Round 13
// 53.239 us; speedup vs baseline: 1.1960x; 1.1960x over previous
//
#include <hip/hip_runtime.h>

#define CLD_NATOMS 8192
#define CLD_NSHIFT 14
#define CLD_NROWS (CLD_NSHIFT * CLD_NATOMS)  // 114688 rows = (k, i)
#define CLD_NTILE 112                        // scan tiles of 1024 rows
#define CLD_NCELL 512                        // 8x8x8 spatial bins
#define CLD_CAP 128                          // max hits per row (k=0 max ~90)
#define CLD_C2 ((float)(5.2 * 5.2))          // f32 compare (JAX weak promotion)
#define CLD_R 5.35f                          // candidate interval half-width

__device__ const int cld_shifts[CLD_NSHIFT][3] = {
    {0, 0, 0},
    {-1, 0, 0}, {-1, -1, 0}, {0, -1, 0}, {1, -1, 0},
    {-1, 1, -1}, {0, 1, -1}, {1, 1, -1}, {-1, 0, -1},
    {0, 0, -1}, {1, 0, -1}, {-1, -1, -1}, {0, -1, -1}, {1, -1, -1}};

// Module-owned scratch (d_ws unused). Everything read is rewritten each call.
__device__ float4 cld_pp[CLD_NATOMS];      // wrapped coords
__device__ int cld_cid[CLD_NATOMS];        // cell id per atom
__device__ float4 cld_sorted[CLD_NATOMS];  // bin-sorted coords, .w = original i
__device__ unsigned cld_cstart[CLD_NCELL + 1];
__device__ unsigned cld_cfill[CLD_NCELL];
__device__ int cld_jbuf[(size_t)CLD_NROWS * CLD_CAP];  // per-row sorted hit j's
__device__ unsigned cld_cnt[CLD_NROWS];
__device__ unsigned cld_off[CLD_NROWS];    // exclusive offset WITHIN tile
__device__ unsigned cld_tot[CLD_NTILE];    // per-tile totals
__device__ float4 cld_dg;                  // cell diagonal
__device__ float4 cld_cinv;                // 8/diag per axis
__device__ float4 cld_sf[CLD_NSHIFT];      // s * diag (f32, __fmul_rn)

// --- K1: wrap + cell-id (+ thread (0,0) publishes the derived constants) ----
// frac = x @ inv(cell); frac -= floor(frac); w = frac @ cell   (f32 per-op RN)
__global__ __launch_bounds__(256) void cld_wrapbin(const float* __restrict__ coords,
                                                   const float* __restrict__ cell) {
  int i = blockIdx.x * blockDim.x + threadIdx.x;
  if (i >= CLD_NATOMS) return;
  // per-thread derived constants (bit-identical everywhere: same f64 ops)
  float dgx = (float)sqrt((double)cell[0] * cell[0] + (double)cell[3] * cell[3] +
                          (double)cell[6] * cell[6]);
  float dgy = (float)sqrt((double)cell[1] * cell[1] + (double)cell[4] * cell[4] +
                          (double)cell[7] * cell[7]);
  float dgz = (float)sqrt((double)cell[2] * cell[2] + (double)cell[5] * cell[5] +
                          (double)cell[8] * cell[8]);
  float cix = 8.0f / dgx, ciy = 8.0f / dgy, ciz = 8.0f / dgz;
  if (i == 0) {
    cld_dg = make_float4(dgx, dgy, dgz, 0.f);
    cld_cinv = make_float4(cix, ciy, ciz, 0.f);
    for (int k = 0; k < CLD_NSHIFT; ++k)
      cld_sf[k] = make_float4(__fmul_rn((float)cld_shifts[k][0], dgx),
                              __fmul_rn((float)cld_shifts[k][1], dgy),
                              __fmul_rn((float)cld_shifts[k][2], dgz), 0.f);
  }

  double a00 = cell[0], a01 = cell[1], a02 = cell[2];
  double a10 = cell[3], a11 = cell[4], a12 = cell[5];
  double a20 = cell[6], a21 = cell[7], a22 = cell[8];
  double det = a00 * (a11 * a22 - a12 * a21) - a01 * (a10 * a22 - a12 * a20) +
               a02 * (a10 * a21 - a11 * a20);
  double id = 1.0 / det;
  float inv[3][3];
  inv[0][0] = (float)((a11 * a22 - a12 * a21) * id);
  inv[0][1] = (float)(-(a01 * a22 - a02 * a21) * id);
  inv[0][2] = (float)((a01 * a12 - a02 * a11) * id);
  inv[1][0] = (float)(-(a10 * a22 - a12 * a20) * id);
  inv[1][1] = (float)((a00 * a22 - a02 * a20) * id);
  inv[1][2] = (float)(-(a00 * a12 - a02 * a10) * id);
  inv[2][0] = (float)((a10 * a21 - a11 * a20) * id);
  inv[2][1] = (float)(-(a00 * a21 - a01 * a20) * id);
  inv[2][2] = (float)((a00 * a11 - a01 * a10) * id);

  float x = coords[3 * i], y = coords[3 * i + 1], z = coords[3 * i + 2];
  float fr[3], w[3];
#pragma unroll
  for (int c = 0; c < 3; ++c) {
    float f = __fadd_rn(__fadd_rn(__fmul_rn(x, inv[0][c]), __fmul_rn(y, inv[1][c])),
                        __fmul_rn(z, inv[2][c]));
    fr[c] = __fsub_rn(f, floorf(f));
  }
#pragma unroll
  for (int c = 0; c < 3; ++c) {
    w[c] = __fadd_rn(
        __fadd_rn(__fmul_rn(fr[0], cell[0 * 3 + c]), __fmul_rn(fr[1], cell[1 * 3 + c])),
        __fmul_rn(fr[2], cell[2 * 3 + c]));
  }
  cld_pp[i] = make_float4(w[0], w[1], w[2], 0.0f);
  int cx = min(7, (int)(w[0] * cix));
  int cy = min(7, (int)(w[1] * ciy));
  int cz = min(7, (int)(w[2] * ciz));
  cld_cid[i] = (cz * 8 + cy) * 8 + cx;  // x fastest -> contiguous x-runs
}

// --- K2: LDS histogram from cid + exclusive scan of 512 cell counts ---------
// (rewrites cstart/cfill fresh each call -> no stale state across replays)
__global__ __launch_bounds__(1024) void cld_cscan() {
  __shared__ unsigned h[CLD_NCELL];
  int t = threadIdx.x;
  if (t < CLD_NCELL) h[t] = 0u;
  __syncthreads();
#pragma unroll
  for (int r = 0; r < 8; ++r) atomicAdd(&h[cld_cid[t + r * 1024]], 1u);
  __syncthreads();
  unsigned v = (t < CLD_NCELL) ? h[t] : 0u;
  unsigned acc = v;
  for (int off = 1; off < CLD_NCELL; off <<= 1) {
    unsigned a = (t >= off && t < CLD_NCELL) ? h[t - off] : 0u;
    __syncthreads();
    if (t < CLD_NCELL) {
      acc += a;
      h[t] = acc;
    }
    __syncthreads();
  }
  if (t < CLD_NCELL) {
    cld_cstart[t] = acc - v;
    cld_cfill[t] = acc - v;
  }
  if (t == CLD_NCELL - 1) cld_cstart[CLD_NCELL] = acc;
}

// --- K3: scatter: bin-sort atoms (intra-cell order nondeterministic; output-
// invariant since hits become bits keyed by original index) ------------------
__global__ __launch_bounds__(256) void cld_scatter() {
  int i = blockIdx.x * blockDim.x + threadIdx.x;
  if (i >= CLD_NATOMS) return;
  unsigned pos = atomicAdd(&cld_cfill[cld_cid[i]], 1u);
  float4 p = cld_pp[i];
  p.w = __int_as_float(i);
  cld_sorted[pos] = p;
}

// Slab prune: d2<=c2 forces shifted atom i into a cutoff-wide boundary slab.
__device__ __forceinline__ bool cld_alive(float xi, float yi, float zi, int sx, int sy,
                                          int sz, float dgx, float dgy, float dgz) {
  bool a = true;
  if (sx < 0) a = a && (xi >= dgx - 5.3f); else if (sx > 0) a = a && (xi <= 5.3f);
  if (sy < 0) a = a && (yi >= dgy - 5.3f); else if (sy > 0) a = a && (yi <= 5.3f);
  if (sz < 0) a = a && (zi >= dgz - 5.3f); else if (sz > 0) a = a && (zi <= 5.3f);
  return a;
}

// Candidate cell range on one axis (monotone-rounding safe, 0.14 slack).
__device__ __forceinline__ void cld_crange(float t, float ci, int& lo, int& hi) {
  lo = max(0, (int)(fmaxf(t - CLD_R, 0.f) * ci));
  hi = min(7, (int)(fmaxf(t + CLD_R, 0.f) * ci));
}

__device__ __forceinline__ unsigned cld_iscan(unsigned v, int lane) {
  for (int off = 1; off < 64; off <<= 1) {
    unsigned t = __shfl_up(v, off);
    if (lane >= off) v += t;
  }
  return v;
}

// --- K4: count: one wave per (k,i) row; cell-list candidates -> LDS bitmask
// -> in-wave expansion to a SORTED compact j-list + row count ----------------
__global__ __launch_bounds__(512) void cld_count() {
  __shared__ uint4 smask[8][64];  // 1KB mask per wave
  int wslot = threadIdx.x >> 6;
  int wv = blockIdx.x * 8 + wslot;
  int lane = threadIdx.x & 63;
  unsigned* lm = (unsigned*)smask[wslot];
  int k = wv >> 13, i = wv & (CLD_NATOMS - 1);

  float4 dg = cld_dg;
  float4 sc = cld_sf[k];
  int sx = cld_shifts[k][0], sy = cld_shifts[k][1], sz = cld_shifts[k][2];
  float4 pi = cld_pp[i];
  if (k != 0 && !cld_alive(pi.x, pi.y, pi.z, sx, sy, sz, dg.x, dg.y, dg.z)) {
    if (lane == 0) cld_cnt[wv] = 0u;
    return;
  }
  smask[wslot][lane] = make_uint4(0u, 0u, 0u, 0u);

  float4 cinv = cld_cinv;
  int xlo, xhi, ylo, yhi, zlo, zhi;
  cld_crange(__fadd_rn(pi.x, sc.x), cinv.x, xlo, xhi);
  cld_crange(__fadd_rn(pi.y, sc.y), cinv.y, ylo, yhi);
  cld_crange(__fadd_rn(pi.z, sc.z), cinv.z, zlo, zhi);

  for (int cz = zlo; cz <= zhi; ++cz) {
    for (int cy = ylo; cy <= yhi; ++cy) {
      int idb = (cz * 8 + cy) * 8;
      unsigned b = cld_cstart[idb + xlo], e = cld_cstart[idb + xhi + 1];
      for (unsigned t = b + lane; t < e; t += 64) {
        float4 pj = cld_sorted[t];
        int j = __float_as_int(pj.w);
        float dx = __fadd_rn(__fsub_rn(pi.x, pj.x), sc.x);
        float dy = __fadd_rn(__fsub_rn(pi.y, pj.y), sc.y);
        float dz = __fadd_rn(__fsub_rn(pi.z, pj.z), sc.z);
        float d2 = __fadd_rn(__fadd_rn(__fmul_rn(dx, dx), __fmul_rn(dy, dy)),
                             __fmul_rn(dz, dz));
        bool ok = (d2 <= CLD_C2) && (k != 0 || i < j);
        if (ok) atomicOr(&lm[(unsigned)j >> 5], 1u << (j & 31));
      }
    }
  }
  __threadfence_block();  // drain LDS atomics before cross-lane mask read

  const unsigned long long* mrow = (const unsigned long long*)lm;
  unsigned long long m0 = mrow[lane];       // j in [64*lane, 64*lane+64)
  unsigned long long m1 = mrow[64 + lane];  // j in [4096+64*lane, ...)
  unsigned c0 = (unsigned)__popcll(m0), c1 = (unsigned)__popcll(m1);
  unsigned s0 = cld_iscan(c0, lane);
  unsigned T0 = __shfl(s0, 63);
  unsigned e0 = s0 - c0;
  unsigned s1 = cld_iscan(c1, lane);
  unsigned T1 = __shfl(s1, 63);
  unsigned e1 = T0 + s1 - c1;

  size_t jb = (size_t)wv * CLD_CAP;
  unsigned p = e0;
  unsigned long long m = m0;
  while (m) {
    int b = __ffsll((long long)m) - 1;
    m &= m - 1;
    if (p < CLD_CAP) cld_jbuf[jb + p] = (lane << 6) + b;
    ++p;
  }
  p = e1;
  m = m1;
  while (m) {
    int b = __ffsll((long long)m) - 1;
    m &= m - 1;
    if (p < CLD_CAP) cld_jbuf[jb + p] = ((64 + lane) << 6) + b;
    ++p;
  }
  if (lane == 0) cld_cnt[wv] = min(T0 + T1, (unsigned)CLD_CAP);
}

// --- K5: per-1024-row tile exclusive scan + tile total ----------------------
__global__ __launch_bounds__(1024) void cld_s1() {
  __shared__ unsigned sd[1024];
  int t = threadIdx.x;
  int gid = blockIdx.x * 1024 + t;
  unsigned v = cld_cnt[gid];
  sd[t] = v;
  __syncthreads();
  unsigned acc = v;
  for (int off = 1; off < 1024; off <<= 1) {
    unsigned a = (t >= off) ? sd[t - off] : 0u;
    __syncthreads();
    acc += a;
    sd[t] = acc;
    __syncthreads();
  }
  cld_off[gid] = acc - v;
  if (t == 1023) cld_tot[blockIdx.x] = acc;
}

// --- K6: emit: one wave per row; wave reduces preceding tile totals (<=112,
// L2-hot) for its base, then lanes copy the compact j-list into the int32
// stream [ i xP | j xP | (sx,sy,sz) xP ] coalesced ---------------------------
__global__ __launch_bounds__(512) void cld_emit(int* __restrict__ out, int P) {
  int wv = blockIdx.x * 8 + (threadIdx.x >> 6);
  int lane = threadIdx.x & 63;
  unsigned c = cld_cnt[wv];  // wave-uniform
  if (c == 0) return;
  int tile = wv >> 10;  // 1024 rows per tile
  unsigned v = 0;
  if (lane < tile) v = cld_tot[lane];
  if (64 + lane < tile) v += cld_tot[64 + lane];
#pragma unroll
  for (int off = 32; off; off >>= 1) v += __shfl_down(v, off);
  unsigned tbase = __shfl(v, 0);

  unsigned off0 = cld_off[wv] + tbase;
  int k = wv >> 13, i = wv & (CLD_NATOMS - 1);
  int sx = cld_shifts[k][0], sy = cld_shifts[k][1], sz = cld_shifts[k][2];
  size_t jb = (size_t)wv * CLD_CAP;
  for (unsigned q = lane; q < c; q += 64) {
    unsigned p = off0 + q;
    if (p < (unsigned)P) {
      out[p] = i;
      out[P + p] = cld_jbuf[jb + q];
      unsigned sp = 2u * (unsigned)P + 3u * p;
      out[sp] = sx;
      out[sp + 1] = sy;
      out[sp + 2] = sz;
    }
  }
}

extern "C" void kernel_launch(void* const* d_in, const int* in_sizes, int n_in,
                              void* d_out, int out_size, void* d_ws, size_t ws_size,
                              hipStream_t stream) {
  const float* coords = (const float*)d_in[1];  // (1, N, 3) f32
  const float* cell = (const float*)d_in[2];    // (3, 3) f32
  int P = out_size / 5;

  cld_wrapbin<<<CLD_NATOMS / 256, 256, 0, stream>>>(coords, cell);
  cld_cscan<<<1, 1024, 0, stream>>>();
  cld_scatter<<<CLD_NATOMS / 256, 256, 0, stream>>>();
  cld_count<<<CLD_NROWS / 8, 512, 0, stream>>>();
  cld_s1<<<CLD_NTILE, 1024, 0, stream>>>();
  cld_emit<<<CLD_NROWS / 8, 512, 0, stream>>>((int*)d_out, P);
}

// Round 15
// 45.081 us; speedup vs baseline: 1.4124x; 1.1810x over previous
//
#include <hip/hip_runtime.h>

#define CLF_NATOMS 8192
#define CLF_NSHIFT 14
#define CLF_NROWS (CLF_NSHIFT * CLF_NATOMS)  // 114688 rows = (k, i)
#define CLF_NTILE 112                        // scan tiles of 1024 rows
#define CLF_NCELL 512                        // 8x8x8 spatial bins
#define CLF_CAP 128                          // max hits per row (k=0 max ~90)
#define CLF_PWAVES 8192                      // persistent waves (1024 blk x 8)
#define CLF_C2 ((float)(5.2 * 5.2))          // f32 compare (JAX weak promotion)
#define CLF_R 5.35f                          // candidate interval half-width

__device__ const int clf_shifts[CLF_NSHIFT][3] = {
    {0, 0, 0},
    {-1, 0, 0}, {-1, -1, 0}, {0, -1, 0}, {1, -1, 0},
    {-1, 1, -1}, {0, 1, -1}, {1, 1, -1}, {-1, 0, -1},
    {0, 0, -1}, {1, 0, -1}, {-1, -1, -1}, {0, -1, -1}, {1, -1, -1}};

// Module-owned scratch (d_ws unused). Everything read is rewritten each call.
__device__ float4 clf_pp[CLF_NATOMS];      // wrapped coords
__device__ int clf_cid[CLF_NATOMS];        // cell id per atom
__device__ float4 clf_sorted[CLF_NATOMS];  // bin-sorted coords, .w = original i
__device__ unsigned clf_cstart[CLF_NCELL + 1];
__device__ unsigned clf_cfill[CLF_NCELL];
__device__ unsigned clf_nalive;            // alive-row count (reset in K1)
__device__ unsigned clf_alist[CLF_NROWS];  // alive row ids (k<<13 | i)
__device__ int clf_jbuf[(size_t)CLF_NROWS * CLF_CAP];  // per-row sorted hit j's
__device__ unsigned clf_cnt[CLF_NROWS];
__device__ unsigned clf_off[CLF_NROWS];    // exclusive offset WITHIN tile
__device__ unsigned clf_tot[CLF_NTILE];    // per-tile totals
__device__ float4 clf_dg;                  // cell diagonal
__device__ float4 clf_cinv;                // 8/diag per axis
__device__ float4 clf_sf[CLF_NSHIFT];      // s * diag (f32, __fmul_rn)

// Slab prune: d2<=c2 forces shifted atom i into a cutoff-wide boundary slab.
__device__ __forceinline__ bool clf_alive(float xi, float yi, float zi, int sx, int sy,
                                          int sz, float dgx, float dgy, float dgz) {
  bool a = true;
  if (sx < 0) a = a && (xi >= dgx - 5.3f); else if (sx > 0) a = a && (xi <= 5.3f);
  if (sy < 0) a = a && (yi >= dgy - 5.3f); else if (sy > 0) a = a && (yi <= 5.3f);
  if (sz < 0) a = a && (zi >= dgz - 5.3f); else if (sz > 0) a = a && (zi <= 5.3f);
  return a;
}

// --- K1: wrap + cell-id; zero cnt[]; reset alive counter; publish consts ----
// frac = x @ inv(cell); frac -= floor(frac); w = frac @ cell   (f32 per-op RN)
__global__ __launch_bounds__(256) void clf_wrapbin(const float* __restrict__ coords,
                                                   const float* __restrict__ cell) {
  int i = blockIdx.x * blockDim.x + threadIdx.x;
  if (i >= CLF_NATOMS) return;
  float dgx = (float)sqrt((double)cell[0] * cell[0] + (double)cell[3] * cell[3] +
                          (double)cell[6] * cell[6]);
  float dgy = (float)sqrt((double)cell[1] * cell[1] + (double)cell[4] * cell[4] +
                          (double)cell[7] * cell[7]);
  float dgz = (float)sqrt((double)cell[2] * cell[2] + (double)cell[5] * cell[5] +
                          (double)cell[8] * cell[8]);
  float cix = 8.0f / dgx, ciy = 8.0f / dgy, ciz = 8.0f / dgz;
  if (i == 0) {
    clf_dg = make_float4(dgx, dgy, dgz, 0.f);
    clf_cinv = make_float4(cix, ciy, ciz, 0.f);
    clf_nalive = 0u;
    for (int k = 0; k < CLF_NSHIFT; ++k)
      clf_sf[k] = make_float4(__fmul_rn((float)clf_shifts[k][0], dgx),
                              __fmul_rn((float)clf_shifts[k][1], dgy),
                              __fmul_rn((float)clf_shifts[k][2], dgz), 0.f);
  }
#pragma unroll
  for (int k = 0; k < CLF_NSHIFT; ++k) clf_cnt[(k << 13) + i] = 0u;  // coalesced

  double a00 = cell[0], a01 = cell[1], a02 = cell[2];
  double a10 = cell[3], a11 = cell[4], a12 = cell[5];
  double a20 = cell[6], a21 = cell[7], a22 = cell[8];
  double det = a00 * (a11 * a22 - a12 * a21) - a01 * (a10 * a22 - a12 * a20) +
               a02 * (a10 * a21 - a11 * a20);
  double id = 1.0 / det;
  float inv[3][3];
  inv[0][0] = (float)((a11 * a22 - a12 * a21) * id);
  inv[0][1] = (float)(-(a01 * a22 - a02 * a21) * id);
  inv[0][2] = (float)((a01 * a12 - a02 * a11) * id);
  inv[1][0] = (float)(-(a10 * a22 - a12 * a20) * id);
  inv[1][1] = (float)((a00 * a22 - a02 * a20) * id);
  inv[1][2] = (float)(-(a00 * a12 - a02 * a10) * id);
  inv[2][0] = (float)((a10 * a21 - a11 * a20) * id);
  inv[2][1] = (float)(-(a00 * a21 - a01 * a20) * id);
  inv[2][2] = (float)((a00 * a11 - a01 * a10) * id);

  float x = coords[3 * i], y = coords[3 * i + 1], z = coords[3 * i + 2];
  float fr[3], w[3];
#pragma unroll
  for (int c = 0; c < 3; ++c) {
    float f = __fadd_rn(__fadd_rn(__fmul_rn(x, inv[0][c]), __fmul_rn(y, inv[1][c])),
                        __fmul_rn(z, inv[2][c]));
    fr[c] = __fsub_rn(f, floorf(f));
  }
#pragma unroll
  for (int c = 0; c < 3; ++c) {
    w[c] = __fadd_rn(
        __fadd_rn(__fmul_rn(fr[0], cell[0 * 3 + c]), __fmul_rn(fr[1], cell[1 * 3 + c])),
        __fmul_rn(fr[2], cell[2 * 3 + c]));
  }
  clf_pp[i] = make_float4(w[0], w[1], w[2], 0.0f);
  int cx = min(7, (int)(w[0] * cix));
  int cy = min(7, (int)(w[1] * ciy));
  int cz = min(7, (int)(w[2] * ciz));
  clf_cid[i] = (cz * 8 + cy) * 8 + cx;  // x fastest -> contiguous x-runs
}

// --- K2: LDS histogram from cid + exclusive scan of 512 cell counts ---------
__global__ __launch_bounds__(1024) void clf_cscan() {
  __shared__ unsigned h[CLF_NCELL];
  int t = threadIdx.x;
  if (t < CLF_NCELL) h[t] = 0u;
  __syncthreads();
#pragma unroll
  for (int r = 0; r < 8; ++r) atomicAdd(&h[clf_cid[t + r * 1024]], 1u);
  __syncthreads();
  unsigned v = (t < CLF_NCELL) ? h[t] : 0u;
  unsigned acc = v;
  for (int off = 1; off < CLF_NCELL; off <<= 1) {
    unsigned a = (t >= off && t < CLF_NCELL) ? h[t - off] : 0u;
    __syncthreads();
    if (t < CLF_NCELL) {
      acc += a;
      h[t] = acc;
    }
    __syncthreads();
  }
  if (t < CLF_NCELL) {
    clf_cstart[t] = acc - v;
    clf_cfill[t] = acc - v;
  }
  if (t == CLF_NCELL - 1) clf_cstart[CLF_NCELL] = acc;
}

// --- K3: scatter (bin-sort) + alive-row list build ---------------------------
// (intra-cell order and alist order nondeterministic; both output-invariant:
//  hits are keyed by original index, rows own their cnt/jbuf slots)
__global__ __launch_bounds__(256) void clf_scatter() {
  int i = blockIdx.x * blockDim.x + threadIdx.x;
  if (i >= CLF_NATOMS) return;
  float4 p = clf_pp[i];
  unsigned pos = atomicAdd(&clf_cfill[clf_cid[i]], 1u);
  float4 ps = p;
  ps.w = __int_as_float(i);
  clf_sorted[pos] = ps;

  // build alive (k,i) row list
  float4 dg = clf_dg;
  unsigned rows[CLF_NSHIFT];
  int m = 0;
  rows[m++] = (unsigned)i;  // k = 0 always alive
#pragma unroll
  for (int k = 1; k < CLF_NSHIFT; ++k) {
    if (clf_alive(p.x, p.y, p.z, clf_shifts[k][0], clf_shifts[k][1], clf_shifts[k][2],
                  dg.x, dg.y, dg.z))
      rows[m++] = (unsigned)((k << 13) + i);
  }
  unsigned base = atomicAdd(&clf_nalive, (unsigned)m);
  for (int q = 0; q < m; ++q) clf_alist[base + q] = rows[q];
}

// Candidate cell range on one axis (monotone-rounding safe, 0.14 slack).
__device__ __forceinline__ void clf_crange(float t, float ci, int& lo, int& hi) {
  lo = max(0, (int)(fmaxf(t - CLF_R, 0.f) * ci));
  hi = min(7, (int)(fmaxf(t + CLF_R, 0.f) * ci));
}

__device__ __forceinline__ unsigned clf_iscan(unsigned v, int lane) {
  for (int off = 1; off < 64; off <<= 1) {
    unsigned t = __shfl_up(v, off);
    if (lane >= off) v += t;
  }
  return v;
}

// --- K4: count: persistent waves over the ALIVE row list; per row:
// cell-list candidates -> LDS bitmask -> sorted compact j-list + count.
// NOTE: NO per-lane state from the divergent candidate loop may feed a
// branch/shuffle in the epilogue (round-14 lesson) — skip test is made
// wave-uniform from the reconverged mask read. ------------------------------
__global__ __launch_bounds__(512) void clf_count() {
  __shared__ uint4 smask[8][64];  // 1KB mask per wave
  int wslot = threadIdx.x >> 6;
  int lane = threadIdx.x & 63;
  unsigned* lm = (unsigned*)smask[wslot];
  unsigned na = clf_nalive;

  float4 cinv = clf_cinv;

  for (unsigned w = blockIdx.x * 8 + wslot; w < na; w += CLF_PWAVES) {
    unsigned row = clf_alist[w];
    int k = row >> 13, i = row & (CLF_NATOMS - 1);
    float4 sc = clf_sf[k];
    float4 pi = clf_pp[i];
    smask[wslot][lane] = make_uint4(0u, 0u, 0u, 0u);

    int xlo, xhi, ylo, yhi, zlo, zhi;
    clf_crange(__fadd_rn(pi.x, sc.x), cinv.x, xlo, xhi);
    clf_crange(__fadd_rn(pi.y, sc.y), cinv.y, ylo, yhi);
    clf_crange(__fadd_rn(pi.z, sc.z), cinv.z, zlo, zhi);

    for (int cz = zlo; cz <= zhi; ++cz) {
      for (int cy = ylo; cy <= yhi; ++cy) {
        int idb = (cz * 8 + cy) * 8;
        unsigned b = clf_cstart[idb + xlo], e = clf_cstart[idb + xhi + 1];
        for (unsigned t = b + lane; t < e; t += 64) {
          float4 pj = clf_sorted[t];
          int j = __float_as_int(pj.w);
          float dx = __fadd_rn(__fsub_rn(pi.x, pj.x), sc.x);
          float dy = __fadd_rn(__fsub_rn(pi.y, pj.y), sc.y);
          float dz = __fadd_rn(__fsub_rn(pi.z, pj.z), sc.z);
          float d2 = __fadd_rn(__fadd_rn(__fmul_rn(dx, dx), __fmul_rn(dy, dy)),
                               __fmul_rn(dz, dz));
          bool ok = (d2 <= CLF_C2) && (k != 0 || i < j);
          if (ok) atomicOr(&lm[(unsigned)j >> 5], 1u << (j & 31));
        }
      }
    }
    __threadfence_block();  // drain LDS atomics; all lanes reconverged here

    const unsigned long long* mrow = (const unsigned long long*)lm;
    unsigned long long m0 = mrow[lane];       // j in [64*lane, 64*lane+64)
    unsigned long long m1 = mrow[64 + lane];  // j in [4096+64*lane, ...)
    // wave-uniform empty-row skip (cnt pre-zeroed in K1)
    if (__ballot((m0 | m1) != 0ull) == 0ull) continue;

    unsigned c0 = (unsigned)__popcll(m0), c1 = (unsigned)__popcll(m1);
    unsigned s0 = clf_iscan(c0, lane);
    unsigned T0 = __shfl(s0, 63);
    unsigned e0 = s0 - c0;
    unsigned s1 = clf_iscan(c1, lane);
    unsigned T1 = __shfl(s1, 63);
    unsigned e1 = T0 + s1 - c1;

    size_t jb = (size_t)row * CLF_CAP;
    unsigned p = e0;
    unsigned long long m = m0;
    while (m) {
      int b = __ffsll((long long)m) - 1;
      m &= m - 1;
      if (p < CLF_CAP) clf_jbuf[jb + p] = (lane << 6) + b;
      ++p;
    }
    p = e1;
    m = m1;
    while (m) {
      int b = __ffsll((long long)m) - 1;
      m &= m - 1;
      if (p < CLF_CAP) clf_jbuf[jb + p] = ((64 + lane) << 6) + b;
      ++p;
    }
    if (lane == 0) clf_cnt[row] = min(T0 + T1, (unsigned)CLF_CAP);
  }
}

// --- K5: per-1024-row tile exclusive scan + tile total ----------------------
__global__ __launch_bounds__(1024) void clf_s1() {
  __shared__ unsigned sd[1024];
  int t = threadIdx.x;
  int gid = blockIdx.x * 1024 + t;
  unsigned v = clf_cnt[gid];
  sd[t] = v;
  __syncthreads();
  unsigned acc = v;
  for (int off = 1; off < 1024; off <<= 1) {
    unsigned a = (t >= off) ? sd[t - off] : 0u;
    __syncthreads();
    acc += a;
    sd[t] = acc;
    __syncthreads();
  }
  clf_off[gid] = acc - v;
  if (t == 1023) clf_tot[blockIdx.x] = acc;
}

// --- K6: emit: persistent waves over the alive list; per row: reduce the
// preceding tile totals (<=112, L2-hot) for the base, then lanes copy the
// compact j-list into [ i xP | j xP | (sx,sy,sz) xP ] coalesced --------------
__global__ __launch_bounds__(512) void clf_emit(int* __restrict__ out, int P) {
  int wslot = threadIdx.x >> 6;
  int lane = threadIdx.x & 63;
  unsigned na = clf_nalive;

  for (unsigned w = blockIdx.x * 8 + wslot; w < na; w += CLF_PWAVES) {
    unsigned row = clf_alist[w];
    unsigned c = clf_cnt[row];  // wave-uniform load
    if (c == 0) continue;       // uniform branch
    int tile = row >> 10;       // 1024 rows per tile
    unsigned v = 0;
    if (lane < tile) v = clf_tot[lane];
    if (64 + lane < tile) v += clf_tot[64 + lane];
#pragma unroll
    for (int off = 32; off; off >>= 1) v += __shfl_down(v, off);
    unsigned tbase = __shfl(v, 0);

    unsigned off0 = clf_off[row] + tbase;
    int k = row >> 13, i = row & (CLF_NATOMS - 1);
    int sx = clf_shifts[k][0], sy = clf_shifts[k][1], sz = clf_shifts[k][2];
    size_t jb = (size_t)row * CLF_CAP;
    for (unsigned q = lane; q < c; q += 64) {
      unsigned p = off0 + q;
      if (p < (unsigned)P) {
        out[p] = i;
        out[P + p] = clf_jbuf[jb + q];
        unsigned sp = 2u * (unsigned)P + 3u * p;
        out[sp] = sx;
        out[sp + 1] = sy;
        out[sp + 2] = sz;
      }
    }
  }
}

extern "C" void kernel_launch(void* const* d_in, const int* in_sizes, int n_in,
                              void* d_out, int out_size, void* d_ws, size_t ws_size,
                              hipStream_t stream) {
  const float* coords = (const float*)d_in[1];  // (1, N, 3) f32
  const float* cell = (const float*)d_in[2];    // (3, 3) f32
  int P = out_size / 5;

  clf_wrapbin<<<CLF_NATOMS / 256, 256, 0, stream>>>(coords, cell);
  clf_cscan<<<1, 1024, 0, stream>>>();
  clf_scatter<<<CLF_NATOMS / 256, 256, 0, stream>>>();
  clf_count<<<CLF_PWAVES / 8, 512, 0, stream>>>();
  clf_s1<<<CLF_NTILE, 1024, 0, stream>>>();
  clf_emit<<<CLF_PWAVES / 8, 512, 0, stream>>>((int*)d_out, P);
}